// Round 1
// baseline (96.151 us; speedup 1.0000x reference)
//
#include <hip/hip_runtime.h>
#include <math.h>

#define VOCAB 32000
#define NROWS 4096
#define PAD_IDX 0

// Per-row kernel: compute rowsum via vectorized loads, then the closed-form
// per-row KL contribution; write partial to workspace (deterministic sum later).
__global__ __launch_bounds__(256) void ls_row_kernel(const float* __restrict__ x,
                                                     const int* __restrict__ target,
                                                     float* __restrict__ partials) {
    const int row = blockIdx.x;
    const float* xr = x + (size_t)row * VOCAB;
    const int tid = threadIdx.x;

    // 32000 floats = 8000 float4 per row
    const float4* x4 = reinterpret_cast<const float4*>(xr);
    float s = 0.f;
    for (int i = tid; i < VOCAB / 4; i += 256) {
        float4 v = x4[i];
        s += (v.x + v.y) + (v.z + v.w);
    }

    // wave-64 reduce
    for (int off = 32; off > 0; off >>= 1)
        s += __shfl_down(s, off, 64);

    __shared__ float ws[4];
    const int wave = tid >> 6;
    const int lane = tid & 63;
    if (lane == 0) ws[wave] = s;
    __syncthreads();

    if (tid == 0) {
        float rowsum = (ws[0] + ws[1]) + (ws[2] + ws[3]);
        int t = target[row];
        float contrib = 0.f;
        if (t != PAD_IDX) {
            const float eps  = 0.1f / (float)(VOCAB - 2);
            // eps*(V-2)*ln(eps) + conf*ln(conf); eps*(V-2) == 0.1 exactly
            const float C = 0.1f * logf(eps) + 0.9f * logf(0.9f);
            float x0 = xr[0];          // pad column excluded from smoothing mass
            float xt = xr[t];          // gold column (L2-resident: row just streamed)
            contrib = C - eps * (rowsum - x0 - xt) - 0.9f * xt;
        }
        partials[row] = contrib;
    }
}

// Single-block deterministic reduction of the 4096 row partials.
__global__ __launch_bounds__(1024) void ls_reduce_kernel(const float* __restrict__ partials,
                                                         float* __restrict__ out) {
    const int tid = threadIdx.x;
    float s = 0.f;
    for (int i = tid; i < NROWS; i += 1024)
        s += partials[i];

    for (int off = 32; off > 0; off >>= 1)
        s += __shfl_down(s, off, 64);

    __shared__ float ws[16];
    const int wave = tid >> 6;
    const int lane = tid & 63;
    if (lane == 0) ws[wave] = s;
    __syncthreads();

    if (tid == 0) {
        float tot = 0.f;
        for (int w = 0; w < 16; ++w) tot += ws[w];
        *out = tot;   // overwrite (d_out is poisoned, never re-zeroed)
    }
}

extern "C" void kernel_launch(void* const* d_in, const int* in_sizes, int n_in,
                              void* d_out, int out_size, void* d_ws, size_t ws_size,
                              hipStream_t stream) {
    const float* x      = (const float*)d_in[0];
    const int*   target = (const int*)d_in[1];
    float* out      = (float*)d_out;
    float* partials = (float*)d_ws;   // 4096 floats

    ls_row_kernel<<<NROWS, 256, 0, stream>>>(x, target, partials);
    ls_reduce_kernel<<<1, 1024, 0, stream>>>(partials, out);
}